// Round 8
// baseline (575.238 us; speedup 1.0000x reference)
//
#include <hip/hip_runtime.h>
#include <math.h>

#define B_   16
#define L_   256
#define V_   50000
#define NV_  50100
#define E_   128
#define H_   128
#define G4_  512
#define CHUNK_  1566   // ceil(50100/32)
#define CHUNKP_ 6263   // ceil(50100/8)

typedef float f32x4 __attribute__((ext_vector_type(4)));
typedef float f32x2 __attribute__((ext_vector_type(2)));
typedef short bf16x8 __attribute__((ext_vector_type(8)));   // 8 bf16 = 4 VGPRs (guide §3)
typedef unsigned int u32x2 __attribute__((ext_vector_type(2)));
typedef unsigned int u32x4 __attribute__((ext_vector_type(4)));

__device__ __forceinline__ float sigm(float x){ return 1.0f/(1.0f+__expf(-x)); }
__device__ __forceinline__ float tanh_fast(float x){
  x = fminf(15.0f, fmaxf(-15.0f, x));
  float t = __expf(2.0f*x);
  return (t-1.0f)/(t+1.0f);
}
__device__ __forceinline__ unsigned int rne_bf16(float f){
  unsigned int x = __float_as_uint(f);
  return (x + 0x7FFFu + ((x>>16)&1u)) >> 16;
}
__device__ __forceinline__ unsigned int pack_bf2(float lo, float hi){
  return rne_bf16(lo) | (rne_bf16(hi) << 16);
}

// ---------------- K1: encoder xg = emb[tok] @ W_ih^T + b ----------------
__global__ __launch_bounds__(512) void enc_xg_kernel(
    const int* __restrict__ tok, const float* __restrict__ emb,
    const float* __restrict__ Wih, const float* __restrict__ bias,
    float* __restrict__ xg)
{
  __shared__ __align__(16) float sx[16*128];
  int r0 = blockIdx.x*16;
  int t = threadIdx.x;
  for (int i=t; i<16*128; i+=512){
    int r=i>>7, e=i&127;
    sx[i] = emb[(size_t)tok[r0+r]*E_ + e];
  }
  __syncthreads();
  int g = t;
  float acc[16];
  #pragma unroll
  for (int r=0;r<16;r++) acc[r]=0.f;
  const f32x4* wr = (const f32x4*)(Wih + (size_t)g*E_);
  #pragma unroll 2
  for (int i=0;i<32;i++){
    f32x4 w = wr[i];
    #pragma unroll
    for (int r=0;r<16;r++){
      f32x4 x = ((const f32x4*)(sx + r*128))[i];
      acc[r] += w.x*x.x + w.y*x.y + w.z*x.z + w.w*x.w;
    }
  }
  float bg = bias[g];
  #pragma unroll
  for (int r=0;r<16;r++) xg[(size_t)(r0+r)*G4_ + g] = acc[r] + bg;
}

// ---------------- K2: encoder LSTM recurrence, MFMA-batched ----------------
// ONE block, 8 waves, all 16 batches as the N-dim of a per-step matmul
// (512x128 bf16 W)@(128x16 bf16 h), fp32 MFMA accumulate.
// - W_hh bf16 in LDS (128KB, XOR-swizzled (row&7)<<4) -> 128KB/step LDS
//   instead of 256KB/step L2 (the R2-R7 measured wall).
// - Wave w owns h-slice [16w,16w+16) across ALL 4 gates (m-tiles at rows
//   {0,128,256,384}+16w) -> i,f,g,o for (k,b) are in the SAME lane ->
//   lane-local c/h update, no gate-exchange LDS, ONE barrier/step.
// - h double-buffered in LDS as bf16 [2][16][128] (swizzled); per-step B
//   fragments via ds_read_b128 (layout per m156: k=(l>>4)*8+j, n=l&15).
__global__ __launch_bounds__(512, 1) void enc_lstm_mfma_kernel(
    const float* __restrict__ xg, const float* __restrict__ Whh,
    float* __restrict__ enc_out)
{
  __shared__ __align__(16) char smem[131072 + 2*4096];
  char* Wl = smem;             // 512 rows x 128 bf16, swizzled
  char* hb = smem + 131072;    // 2 x [16 batches][128 k] bf16, swizzled

  const int tid  = threadIdx.x;
  const int lane = tid & 63;
  const int w    = tid >> 6;        // wave 0..7
  const int b    = lane & 15;       // batch (N-col)
  const int kg   = lane >> 4;       // 0..3

  // ---- stage W: fp32 -> bf16 (RNE), swizzled row-major ----
  {
    int g = tid;  // one row per thread
    const f32x4* src = (const f32x4*)(Whh + (size_t)g*H_);
    unsigned swz = (unsigned)((g & 7) << 4);
    #pragma unroll 4
    for (int j=0;j<16;j++){
      f32x4 v0 = src[2*j], v1 = src[2*j+1];
      u32x4 pk;
      pk.x = pack_bf2(v0.x, v0.y);
      pk.y = pack_bf2(v0.z, v0.w);
      pk.z = pack_bf2(v1.x, v1.y);
      pk.w = pack_bf2(v1.z, v1.w);
      *(u32x4*)(Wl + (((unsigned)(g*256 + j*16)) ^ swz)) = pk;
    }
  }
  // ---- zero h buffers ----
  {
    u32x2* p = (u32x2*)hb;
    for (int i=tid;i<1024;i+=512) p[i] = (u32x2){0u,0u};
  }
  __syncthreads();

  // per-lane constant offsets
  const unsigned swzA = (unsigned)((lane & 7) << 4);
  const unsigned swzB = (unsigned)((b & 7) << 4);
  const unsigned xa0 = ((0*64) | (kg*16)) ^ swzA;
  const unsigned xa1 = ((1*64) | (kg*16)) ^ swzA;
  const unsigned xa2 = ((2*64) | (kg*16)) ^ swzA;
  const unsigned xa3 = ((3*64) | (kg*16)) ^ swzA;
  const unsigned xb0 = ((0*64) | (kg*16)) ^ swzB;
  const unsigned xb1 = ((1*64) | (kg*16)) ^ swzB;
  const unsigned xb2 = ((2*64) | (kg*16)) ^ swzB;
  const unsigned xb3 = ((3*64) | (kg*16)) ^ swzB;
  const unsigned rbI = (unsigned)((0*128 + w*16 + (lane & 15)) * 256);
  const unsigned rbF = (unsigned)((1*128 + w*16 + (lane & 15)) * 256);
  const unsigned rbG = (unsigned)((2*128 + w*16 + (lane & 15)) * 256);
  const unsigned rbO = (unsigned)((3*128 + w*16 + (lane & 15)) * 256);
  const unsigned hwoff = (unsigned)(((w*32 + kg*8) ^ swzB) + b*256);
  const int k0 = w*16 + kg*4;

  float c0=0.f, c1=0.f, c2=0.f, c3=0.f;

  // xg preload for s=0
  const float* xq0 = xg + ((size_t)b*256 + 0)*512 + k0;
  f32x4 xgcI = *(const f32x4*)(xq0);
  f32x4 xgcF = *(const f32x4*)(xq0 + 128);
  f32x4 xgcG = *(const f32x4*)(xq0 + 256);
  f32x4 xgcO = *(const f32x4*)(xq0 + 384);

  int cur = 0;
  for (int s=0; s<L_; s++){
    // prefetch xg for s+1 (hidden under this step's LDS/MFMA)
    int s2 = (s < L_-1) ? s+1 : L_-1;
    const float* xq = xg + ((size_t)b*256 + s2)*512 + k0;
    f32x4 xgnI = *(const f32x4*)(xq);
    f32x4 xgnF = *(const f32x4*)(xq + 128);
    f32x4 xgnG = *(const f32x4*)(xq + 256);
    f32x4 xgnO = *(const f32x4*)(xq + 384);

    // B fragments: h (bf16) from hb[cur]
    const char* hbc = hb + cur*4096 + b*256;
    bf16x8 bf0 = *(const bf16x8*)(hbc + xb0);
    bf16x8 bf1 = *(const bf16x8*)(hbc + xb1);
    bf16x8 bf2 = *(const bf16x8*)(hbc + xb2);
    bf16x8 bf3 = *(const bf16x8*)(hbc + xb3);

    // 16 MFMAs: 4 gate-tiles x 4 k-slices, acc init = xg
    f32x4 aI = xgcI, aF = xgcF, aG = xgcG, aO = xgcO;
    aI = __builtin_amdgcn_mfma_f32_16x16x32_bf16(*(const bf16x8*)(Wl + rbI + xa0), bf0, aI, 0,0,0);
    aF = __builtin_amdgcn_mfma_f32_16x16x32_bf16(*(const bf16x8*)(Wl + rbF + xa0), bf0, aF, 0,0,0);
    aG = __builtin_amdgcn_mfma_f32_16x16x32_bf16(*(const bf16x8*)(Wl + rbG + xa0), bf0, aG, 0,0,0);
    aO = __builtin_amdgcn_mfma_f32_16x16x32_bf16(*(const bf16x8*)(Wl + rbO + xa0), bf0, aO, 0,0,0);
    aI = __builtin_amdgcn_mfma_f32_16x16x32_bf16(*(const bf16x8*)(Wl + rbI + xa1), bf1, aI, 0,0,0);
    aF = __builtin_amdgcn_mfma_f32_16x16x32_bf16(*(const bf16x8*)(Wl + rbF + xa1), bf1, aF, 0,0,0);
    aG = __builtin_amdgcn_mfma_f32_16x16x32_bf16(*(const bf16x8*)(Wl + rbG + xa1), bf1, aG, 0,0,0);
    aO = __builtin_amdgcn_mfma_f32_16x16x32_bf16(*(const bf16x8*)(Wl + rbO + xa1), bf1, aO, 0,0,0);
    aI = __builtin_amdgcn_mfma_f32_16x16x32_bf16(*(const bf16x8*)(Wl + rbI + xa2), bf2, aI, 0,0,0);
    aF = __builtin_amdgcn_mfma_f32_16x16x32_bf16(*(const bf16x8*)(Wl + rbF + xa2), bf2, aF, 0,0,0);
    aG = __builtin_amdgcn_mfma_f32_16x16x32_bf16(*(const bf16x8*)(Wl + rbG + xa2), bf2, aG, 0,0,0);
    aO = __builtin_amdgcn_mfma_f32_16x16x32_bf16(*(const bf16x8*)(Wl + rbO + xa2), bf2, aO, 0,0,0);
    aI = __builtin_amdgcn_mfma_f32_16x16x32_bf16(*(const bf16x8*)(Wl + rbI + xa3), bf3, aI, 0,0,0);
    aF = __builtin_amdgcn_mfma_f32_16x16x32_bf16(*(const bf16x8*)(Wl + rbF + xa3), bf3, aF, 0,0,0);
    aG = __builtin_amdgcn_mfma_f32_16x16x32_bf16(*(const bf16x8*)(Wl + rbG + xa3), bf3, aG, 0,0,0);
    aO = __builtin_amdgcn_mfma_f32_16x16x32_bf16(*(const bf16x8*)(Wl + rbO + xa3), bf3, aO, 0,0,0);

    // lane-local epilogue: c,h for (k0+reg, b)
    float i0=sigm(aI.x), i1=sigm(aI.y), i2=sigm(aI.z), i3=sigm(aI.w);
    float f0=sigm(aF.x), f1=sigm(aF.y), f2=sigm(aF.z), f3=sigm(aF.w);
    float g0=tanh_fast(aG.x), g1=tanh_fast(aG.y), g2=tanh_fast(aG.z), g3=tanh_fast(aG.w);
    float o0=sigm(aO.x), o1=sigm(aO.y), o2=sigm(aO.z), o3=sigm(aO.w);
    c0 = f0*c0 + i0*g0;  float h0 = o0*tanh_fast(c0);
    c1 = f1*c1 + i1*g1;  float h1 = o1*tanh_fast(c1);
    c2 = f2*c2 + i2*g2;  float h2 = o2*tanh_fast(c2);
    c3 = f3*c3 + i3*g3;  float h3 = o3*tanh_fast(c3);

    // fp32 h -> enc_out
    *(f32x4*)(enc_out + ((size_t)b*256 + s)*128 + k0) = (f32x4){h0,h1,h2,h3};
    // bf16 h -> hb[cur^1]
    u32x2 hp; hp.x = pack_bf2(h0,h1); hp.y = pack_bf2(h2,h3);
    *(u32x2*)(hb + (cur^1)*4096 + hwoff) = hp;

    __syncthreads();
    cur ^= 1;
    xgcI = xgnI; xgcF = xgnF; xgcG = xgnG; xgcO = xgnO;
  }
}

// ---------------- fused: [blocks 0-15] mid chain  /  [blocks 16-31] token agg ----------------
__global__ __launch_bounds__(512) void midagg_kernel(
    const int* __restrict__ src, const int* __restrict__ prev,
    const float* __restrict__ enc_out, const float* __restrict__ cW,
    const float* __restrict__ dstate, const float* __restrict__ emb,
    const float* __restrict__ dWih, const float* __restrict__ db,
    const float* __restrict__ aW, const float* __restrict__ oW,
    const float* __restrict__ ob, float* __restrict__ attn_out,
    const int* __restrict__ stw, float* __restrict__ agg,
    int* __restrict__ replist, int* __restrict__ repcnt)
{
  int t=threadIdx.x;
  if (blockIdx.x >= 16){
    // ======== copy_agg path (first-occurrence aggregation) ========
    int b = blockIdx.x - 16;
    __shared__ int stok[256];
    __shared__ int scnt;
    if (t<256) stok[t] = stw[b*L_+t];
    if (t==0) scnt=0;
    __syncthreads();
    if (t<256){
      int tok = stok[t];
      int first=0;
      while (stok[first]!=tok) first++;
      if (first==t){
        int myidx = atomicAdd(&scnt,1);
        f32x4 acc[32];
        #pragma unroll
        for (int i=0;i<32;i++) acc[i]=(f32x4){0.f,0.f,0.f,0.f};
        for (int l2=t; l2<L_; l2++){
          if (stok[l2]==tok){
            const f32x4* e=(const f32x4*)(enc_out + ((size_t)b*L_+l2)*H_);
            #pragma unroll
            for (int i=0;i<32;i++) acc[i]+=e[i];
          }
        }
        f32x4* dst=(f32x4*)(agg + ((size_t)b*L_+t)*H_);
        #pragma unroll
        for (int i=0;i<32;i++) dst[i]=acc[i];
        replist[b*L_+myidx]=t;
      }
    }
    __syncthreads();
    if (t==0) repcnt[b]=scnt;
    return;
  }

  // ======== mid path: copy scores + copy softmax/state + dec step + attention ========
  int b=blockIdx.x;
  __shared__ float s_scopy[256];
  __shared__ int   mlist[256];
  __shared__ int   mcnt;
  __shared__ __align__(16) float se[128];
  __shared__ float sw[256];
  __shared__ float spart[512];
  __shared__ float sred[4];
  __shared__ __align__(16) float sin_[256];
  __shared__ float sg[512];
  __shared__ __align__(16) float sr[128];
  __shared__ __align__(16) float sq[128];
  __shared__ float sc[256];
  __shared__ __align__(16) float sctx[128];

  if (t==0) mcnt=0;
  __syncthreads();
  if (t<256){
    s_scopy[t]=0.f;
    if (src[b*L_+t]==prev[b]){ int i=atomicAdd(&mcnt,1); mlist[i]=t; }
  }
  __syncthreads();
  for (int mi=0; mi<mcnt; mi++){
    int l = mlist[mi];
    if (t<128) se[t] = enc_out[((size_t)b*L_+l)*H_ + t];
    __syncthreads();
    if (t<128){
      const f32x4* wr = (const f32x4*)(cW + (size_t)t*H_);
      const f32x4* e4 = (const f32x4*)se;
      float acc=0.f;
      #pragma unroll
      for (int i=0;i<32;i++){
        f32x4 wv=wr[i], e=e4[i];
        acc += wv.x*e.x + wv.y*e.y + wv.z*e.z + wv.w*e.w;
      }
      float v = tanhf(acc)*dstate[b*H_+t];
      #pragma unroll
      for (int o=32;o;o>>=1) v += __shfl_down(v,o);
      if ((t&63)==0) sred[t>>6]=v;
    }
    __syncthreads();
    if (t==0) s_scopy[l]=sred[0]+sred[1];
    __syncthreads();
  }

  // softmax over copy scores
  float v = (t<256) ? s_scopy[t] : -INFINITY;
  {
    float m=v;
    #pragma unroll
    for (int o=32;o;o>>=1) m=fmaxf(m,__shfl_down(m,o));
    if (t<256 && (t&63)==0) sred[t>>6]=m;
  }
  __syncthreads();
  float m4 = fmaxf(fmaxf(sred[0],sred[1]),fmaxf(sred[2],sred[3]));
  __syncthreads();
  float e = (t<256) ? __expf(v-m4) : 0.f;
  {
    float z=e;
    #pragma unroll
    for (int o=32;o;o>>=1) z += __shfl_down(z,o);
    if (t<256 && (t&63)==0) sred[t>>6]=z;
  }
  __syncthreads();
  {
    float z4 = sred[0]+sred[1]+sred[2]+sred[3];
    if (t<256) sw[t] = e/z4;
  }
  __syncthreads();

  // copy_state
  {
    int ch=t>>7, h=t&127;
    float acc=0.f;
    const float* eb = enc_out + (size_t)b*L_*H_;
    for (int l=ch*64; l<ch*64+64; l++) acc += sw[l]*eb[(size_t)l*H_+h];
    spart[t]=acc;
  }
  __syncthreads();
  if (t<128){
    float cst = spart[t]+spart[128+t]+spart[256+t]+spart[384+t];
    sin_[128+t]=cst;
    sin_[t]=emb[(size_t)prev[b]*E_+t];
  }
  __syncthreads();

  // decoder single LSTM step (h0=c0=0)
  {
    const f32x4* wr=(const f32x4*)(dWih + (size_t)t*256);
    const f32x4* x4=(const f32x4*)sin_;
    f32x2 d0={db[t],0.f}, d1={0.f,0.f}, d2={0.f,0.f}, d3={0.f,0.f};
    #pragma unroll
    for (int k=0;k<64;k+=4){
      f32x4 xa=x4[k], xb=x4[k+1], xc=x4[k+2], xd=x4[k+3];
      f32x4 wva=wr[k], wvb=wr[k+1], wvc=wr[k+2], wvd=wr[k+3];
      d0 += wva.xy*xa.xy; d1 += wva.zw*xa.zw;
      d2 += wvb.xy*xb.xy; d3 += wvb.zw*xb.zw;
      d0 += wvc.xy*xc.xy; d1 += wvc.zw*xc.zw;
      d2 += wvd.xy*xd.xy; d3 += wvd.zw*xd.zw;
    }
    f32x2 dsm=(d0+d1)+(d2+d3);
    sg[t]=dsm.x+dsm.y;
  }
  __syncthreads();
  if (t<128){
    float iv=sg[t], gv=sg[256+t], ov=sg[384+t];
    float cc = sigm(iv)*tanhf(gv);
    sr[t] = sigm(ov)*tanhf(cc);
  }
  __syncthreads();

  // q = attn_W @ rnn
  if (t<128){
    const f32x4* wr=(const f32x4*)(aW + (size_t)t*H_);
    const f32x4* x4=(const f32x4*)sr;
    float acc=0.f;
    #pragma unroll
    for (int i=0;i<32;i++){
      f32x4 wv=wr[i], x=x4[i];
      acc += wv.x*x.x + wv.y*x.y + wv.z*x.z + wv.w*x.w;
    }
    sq[t]=acc;
  }
  __syncthreads();

  // scores + pad mask
  if (t<256){
    const f32x4* e4=(const f32x4*)(enc_out + ((size_t)b*L_+t)*H_);
    const f32x4* q4=(const f32x4*)sq;
    float acc=0.f;
    #pragma unroll
    for (int i=0;i<32;i++){
      f32x4 ev=e4[i], q=q4[i];
      acc += ev.x*q.x + ev.y*q.y + ev.z*q.z + ev.w*q.w;
    }
    if (src[b*L_+t]==0) acc=-INFINITY;
    sc[t]=acc;
  }
  __syncthreads();

  // attn softmax
  v = (t<256) ? sc[t] : -INFINITY;
  {
    float m=v;
    #pragma unroll
    for (int o=32;o;o>>=1) m=fmaxf(m,__shfl_down(m,o));
    if (t<256 && (t&63)==0) sred[t>>6]=m;
  }
  __syncthreads();
  m4 = fmaxf(fmaxf(sred[0],sred[1]),fmaxf(sred[2],sred[3]));
  __syncthreads();
  e = (t<256) ? __expf(v-m4) : 0.f;
  {
    float z=e;
    #pragma unroll
    for (int o=32;o;o>>=1) z += __shfl_down(z,o);
    if (t<256 && (t&63)==0) sred[t>>6]=z;
  }
  __syncthreads();
  {
    float z4 = sred[0]+sred[1]+sred[2]+sred[3];
    if (t<256) sc[t] = e/z4;
  }
  __syncthreads();

  // ctx
  {
    int ch=t>>7, h=t&127;
    float acc=0.f;
    const float* eb = enc_out + (size_t)b*L_*H_;
    for (int l=ch*64; l<ch*64+64; l++) acc += sc[l]*eb[(size_t)l*H_+h];
    spart[t]=acc;
  }
  __syncthreads();
  if (t<128) sctx[t] = spart[t]+spart[128+t]+spart[256+t]+spart[384+t];
  __syncthreads();

  // attn_out = tanh(out_W @ [rnn,ctx] + out_b)
  if (t<128){
    const f32x4* wr=(const f32x4*)(oW + (size_t)t*256);
    const f32x4* r4=(const f32x4*)sr;
    const f32x4* c4=(const f32x4*)sctx;
    float acc=ob[t];
    #pragma unroll
    for (int i=0;i<32;i++){
      f32x4 wv=wr[i], x=r4[i];
      acc += wv.x*x.x + wv.y*x.y + wv.z*x.z + wv.w*x.w;
    }
    #pragma unroll
    for (int i=0;i<32;i++){
      f32x4 wv=wr[32+i], x=c4[i];
      acc += wv.x*x.x + wv.y*x.y + wv.z*x.z + wv.w*x.w;
    }
    attn_out[b*H_+t]=tanhf(acc);
  }
}

// ---------------- K9: gen logits + masks -> total ----------------
__global__ __launch_bounds__(256) void gen_logits_kernel(
    const float* __restrict__ attn_out, const float* __restrict__ gW,
    const int* __restrict__ oovc, float* __restrict__ total)
{
  __shared__ float sa[B_*H_];
  __shared__ float sw[64*129];
  int t=threadIdx.x;
  int v0=blockIdx.x*64;
  for (int i=t;i<B_*H_;i+=256) sa[i]=attn_out[i];
  for (int i=t;i<64*32;i+=256){
    int r=i>>5, cc=i&31;
    if (v0+r<NV_){
      float4 wv = ((const float4*)(gW + (size_t)(v0+r)*H_))[cc];
      float* dst = sw + r*129 + cc*4;
      dst[0]=wv.x; dst[1]=wv.y; dst[2]=wv.z; dst[3]=wv.w;
    }
  }
  __syncthreads();
  int vl=t&63, bq=t>>6;
  int v=v0+vl;
  if (v>=NV_) return;
  float acc[4]={0.f,0.f,0.f,0.f};
  const float* wrow = sw + vl*129;
  #pragma unroll 8
  for (int h4=0; h4<32; h4++){
    float w0=wrow[h4*4+0], w1=wrow[h4*4+1], w2=wrow[h4*4+2], w3=wrow[h4*4+3];
    #pragma unroll
    for (int k=0;k<4;k++){
      float4 a = ((const float4*)(sa + (bq*4+k)*H_))[h4];
      acc[k] += w0*a.x + w1*a.y + w2*a.z + w3*a.w;
    }
  }
  #pragma unroll
  for (int k=0;k<4;k++){
    int b=bq*4+k;
    float o = (v==1 || v >= V_ + oovc[b]) ? -INFINITY : acc[k];
    total[(size_t)b*NV_ + v] = o;
  }
}

// ---------------- K7b: sparse copy scores added into total ----------------
__global__ __launch_bounds__(128) void copy_score2_kernel(
    const int* __restrict__ stw, const float* __restrict__ agg,
    const float* __restrict__ cW, const float* __restrict__ attn_out,
    const int* __restrict__ replist, const int* __restrict__ repcnt,
    float* __restrict__ total)
{
  int b=blockIdx.x;
  int cnt=repcnt[b];
  int g=threadIdx.x;
  __shared__ __align__(16) float srow[128];
  __shared__ float sred[2];
  float aog = attn_out[b*H_+g];
  f32x4 w[32];
  const f32x4* wrow=(const f32x4*)(cW + (size_t)g*H_);
  #pragma unroll
  for (int i=0;i<32;i++) w[i]=wrow[i];
  for (int ri=blockIdx.y; ri<cnt; ri+=gridDim.y){
    int l = replist[b*L_+ri];
    srow[g] = agg[((size_t)b*L_+l)*H_+g];
    __syncthreads();
    float acc=0.f;
    #pragma unroll
    for (int i=0;i<32;i++){
      f32x4 e=((const f32x4*)srow)[i]; f32x4 wv=w[i];
      acc += wv.x*e.x + wv.y*e.y + wv.z*e.z + wv.w*e.w;
    }
    float v = tanhf(acc)*aog;
    #pragma unroll
    for (int o=32;o;o>>=1) v += __shfl_down(v,o);
    if ((g&63)==0) sred[g>>6]=v;
    __syncthreads();
    if (g==0){
      int vtok = stw[b*L_+l];
      total[(size_t)b*NV_ + vtok] += sred[0]+sred[1];
    }
    __syncthreads();
  }
}

// ---------------- K10: vocab softmax (chunked partials + fused finalize) ----------------
__global__ __launch_bounds__(256) void vocab_pass1_kernel(
    const float* __restrict__ total, float* __restrict__ pmax, float* __restrict__ psum)
{
  int b=blockIdx.x, j=blockIdx.y, t=threadIdx.x;
  int lo=j*CHUNKP_, hi=min(lo+CHUNKP_, NV_);
  const float* row = total + (size_t)b*NV_;
  __shared__ float sred[4];
  float m=-INFINITY;
  for (int i=lo+t;i<hi;i+=256) m=fmaxf(m,row[i]);
  #pragma unroll
  for (int o=32;o;o>>=1) m=fmaxf(m,__shfl_down(m,o));
  if ((t&63)==0) sred[t>>6]=m;
  __syncthreads();
  m = fmaxf(fmaxf(sred[0],sred[1]),fmaxf(sred[2],sred[3]));
  __syncthreads();
  float s=0.f;
  if (m > -INFINITY){
    for (int i=lo+t;i<hi;i+=256) s += __expf(row[i]-m);
  }
  #pragma unroll
  for (int o=32;o;o>>=1) s += __shfl_down(s,o);
  if ((t&63)==0) sred[t>>6]=s;
  __syncthreads();
  if (t==0){ pmax[b*8+j]=m; psum[b*8+j]=sred[0]+sred[1]+sred[2]+sred[3]; }
}

__global__ __launch_bounds__(256) void vocab_norm_kernel(
    float* __restrict__ total, const float* __restrict__ pmax,
    const float* __restrict__ psum)
{
  int b=blockIdx.x, j=blockIdx.y, t=threadIdx.x;
  float M=-INFINITY;
  #pragma unroll
  for (int k=0;k<8;k++) M=fmaxf(M,pmax[b*8+k]);
  float Z=0.f;
  #pragma unroll
  for (int k=0;k<8;k++){
    float pj=pmax[b*8+k];
    Z += (pj > -INFINITY) ? psum[b*8+k]*__expf(pj-M) : 0.f;
  }
  float rz=1.0f/Z;
  int lo=j*CHUNK_, hi=min(lo+CHUNK_, NV_);
  float* row = total + (size_t)b*NV_;
  for (int i=lo+t;i<hi;i+=256) row[i] = __expf(row[i]-M)*rz;
}

// ---------------- launch ----------------
extern "C" void kernel_launch(void* const* d_in, const int* in_sizes, int n_in,
                              void* d_out, int out_size, void* d_ws, size_t ws_size,
                              hipStream_t stream)
{
  const int*   src_tokens = (const int*)d_in[0];
  const int*   prev_tok   = (const int*)d_in[2];
  const int*   stw        = (const int*)d_in[4];
  const int*   oovc       = (const int*)d_in[5];
  const float* dstate     = (const float*)d_in[6];
  const float* emb        = (const float*)d_in[7];
  const float* enc_Wih    = (const float*)d_in[8];
  const float* enc_Whh    = (const float*)d_in[9];
  const float* enc_b      = (const float*)d_in[10];
  const float* dec_Wih    = (const float*)d_in[11];
  const float* dec_b      = (const float*)d_in[13];
  const float* attn_W     = (const float*)d_in[14];
  const float* out_W      = (const float*)d_in[15];
  const float* out_b      = (const float*)d_in[16];
  const float* copy_W     = (const float*)d_in[17];
  const float* gen_W      = (const float*)d_in[18];

  float* out      = (float*)d_out;
  float* total    = out;                                 // B*NV
  float* enc_out  = out + (size_t)B_*NV_;                // B*L*H
  float* attn_out = enc_out + (size_t)B_*L_*H_;          // B*H

  float* ws     = (float*)d_ws;
  float* xg     = ws;                                    // B*L*G4
  float* agg    = xg + (size_t)B_*L_*G4_;                // B*L*H
  float* pmax   = agg + (size_t)B_*L_*H_;                // 128
  float* psum   = pmax + 128;                            // 128
  int*   replist= (int*)(psum + 128);                    // B*L
  int*   repcnt = replist + B_*L_;                       // 16

  enc_xg_kernel<<<B_*L_/16, 512, 0, stream>>>(src_tokens, emb, enc_Wih, enc_b, xg);
  enc_lstm_mfma_kernel<<<1, 512, 0, stream>>>(xg, enc_Whh, enc_out);
  midagg_kernel<<<32, 512, 0, stream>>>(src_tokens, prev_tok, enc_out, copy_W, dstate,
                                        emb, dec_Wih, dec_b, attn_W, out_W, out_b, attn_out,
                                        stw, agg, replist, repcnt);
  gen_logits_kernel<<<(NV_+63)/64, 256, 0, stream>>>(attn_out, gen_W, oovc, total);
  copy_score2_kernel<<<dim3(B_,32), 128, 0, stream>>>(stw, agg, copy_W, attn_out, replist, repcnt, total);
  vocab_pass1_kernel<<<dim3(B_,8), 256, 0, stream>>>(total, pmax, psum);
  vocab_norm_kernel<<<dim3(B_,32), 256, 0, stream>>>(total, pmax, psum);
}

// Round 9
// 501.533 us; speedup vs baseline: 1.1470x; 1.1470x over previous
//
#include <hip/hip_runtime.h>
#include <math.h>

#define B_   16
#define L_   256
#define V_   50000
#define NV_  50100
#define E_   128
#define H_   128
#define G4_  512
#define CHUNK_  1566   // ceil(50100/32)
#define CHUNKP_ 6263   // ceil(50100/8)

typedef float f32x4 __attribute__((ext_vector_type(4)));
typedef float f32x2 __attribute__((ext_vector_type(2)));
typedef short bf16x8 __attribute__((ext_vector_type(8)));   // 8 bf16 = 4 VGPRs (guide §3)
typedef unsigned int u32x2 __attribute__((ext_vector_type(2)));
typedef unsigned int u32x4 __attribute__((ext_vector_type(4)));

__device__ __forceinline__ float sigm(float x){ return 1.0f/(1.0f+__expf(-x)); }
__device__ __forceinline__ float tanh_fast(float x){
  x = fminf(15.0f, fmaxf(-15.0f, x));
  float t = __expf(2.0f*x);
  return (t-1.0f)/(t+1.0f);
}
__device__ __forceinline__ unsigned int rne_bf16(float f){
  unsigned int x = __float_as_uint(f);
  return (x + 0x7FFFu + ((x>>16)&1u)) >> 16;
}
__device__ __forceinline__ unsigned int pack_bf2(float lo, float hi){
  return rne_bf16(lo) | (rne_bf16(hi) << 16);
}

// ---------------- K1: encoder xg = emb[tok] @ W_ih^T + b ----------------
__global__ __launch_bounds__(512) void enc_xg_kernel(
    const int* __restrict__ tok, const float* __restrict__ emb,
    const float* __restrict__ Wih, const float* __restrict__ bias,
    float* __restrict__ xg)
{
  __shared__ __align__(16) float sx[16*128];
  int r0 = blockIdx.x*16;
  int t = threadIdx.x;
  for (int i=t; i<16*128; i+=512){
    int r=i>>7, e=i&127;
    sx[i] = emb[(size_t)tok[r0+r]*E_ + e];
  }
  __syncthreads();
  int g = t;
  float acc[16];
  #pragma unroll
  for (int r=0;r<16;r++) acc[r]=0.f;
  const f32x4* wr = (const f32x4*)(Wih + (size_t)g*E_);
  #pragma unroll 2
  for (int i=0;i<32;i++){
    f32x4 w = wr[i];
    #pragma unroll
    for (int r=0;r<16;r++){
      f32x4 x = ((const f32x4*)(sx + r*128))[i];
      acc[r] += w.x*x.x + w.y*x.y + w.z*x.z + w.w*x.w;
    }
  }
  float bg = bias[g];
  #pragma unroll
  for (int r=0;r<16;r++) xg[(size_t)(r0+r)*G4_ + g] = acc[r] + bg;
}

// ---------------- K2: encoder LSTM recurrence, MFMA-batched ----------------
// ONE block, 8 waves, all 16 batches as the N-dim of a per-step matmul
// (512x128 bf16 W)@(128x16 bf16 h), fp32 MFMA accumulate.
// R8 lesson (PMC): re-reading W from LDS every step = 160 ds_read_b128
// wave-instrs through one LDS pipe ~= 1920cy/step -> 4360cy/step total.
// FIX: A-fragments (W) are loop-invariant -> hoist the 16 bf16x8 frags
// into registers (64 VGPRs). Remat back into the loop is ILLEGAL here
// (ds_read of the same LDS object that other threads ds_write each step
// with runtime-XOR addresses -> may-alias), unlike R2-R7's global loads.
// Per-step LDS = 4 B-frag reads + 1 h write only.
__global__ __launch_bounds__(512, 1) void enc_lstm_mfma_kernel(
    const float* __restrict__ xg, const float* __restrict__ Whh,
    float* __restrict__ enc_out)
{
  __shared__ __align__(16) char smem[131072 + 2*4096];
  char* Wl = smem;             // 512 rows x 128 bf16, swizzled
  char* hb = smem + 131072;    // 2 x [16 batches][128 k] bf16, swizzled

  const int tid  = threadIdx.x;
  const int lane = tid & 63;
  const int w    = tid >> 6;        // wave 0..7
  const int b    = lane & 15;       // batch (N-col)
  const int kg   = lane >> 4;       // 0..3

  // ---- stage W: fp32 -> bf16 (RNE), swizzled row-major ----
  {
    int g = tid;  // one row per thread
    const f32x4* src = (const f32x4*)(Whh + (size_t)g*H_);
    unsigned swz = (unsigned)((g & 7) << 4);
    #pragma unroll 4
    for (int j=0;j<16;j++){
      f32x4 v0 = src[2*j], v1 = src[2*j+1];
      u32x4 pk;
      pk.x = pack_bf2(v0.x, v0.y);
      pk.y = pack_bf2(v0.z, v0.w);
      pk.z = pack_bf2(v1.x, v1.y);
      pk.w = pack_bf2(v1.z, v1.w);
      *(u32x4*)(Wl + (((unsigned)(g*256 + j*16)) ^ swz)) = pk;
    }
  }
  // ---- zero h buffers ----
  {
    u32x2* p = (u32x2*)hb;
    for (int i=tid;i<1024;i+=512) p[i] = (u32x2){0u,0u};
  }
  __syncthreads();

  // per-lane constant offsets
  const unsigned swzA = (unsigned)((lane & 7) << 4);
  const unsigned swzB = (unsigned)((b & 7) << 4);
  const unsigned xa0 = ((0*64) | (kg*16)) ^ swzA;
  const unsigned xa1 = ((1*64) | (kg*16)) ^ swzA;
  const unsigned xa2 = ((2*64) | (kg*16)) ^ swzA;
  const unsigned xa3 = ((3*64) | (kg*16)) ^ swzA;
  const unsigned xb0 = ((0*64) | (kg*16)) ^ swzB;
  const unsigned xb1 = ((1*64) | (kg*16)) ^ swzB;
  const unsigned xb2 = ((2*64) | (kg*16)) ^ swzB;
  const unsigned xb3 = ((3*64) | (kg*16)) ^ swzB;
  const unsigned rbI = (unsigned)((0*128 + w*16 + (lane & 15)) * 256);
  const unsigned rbF = (unsigned)((1*128 + w*16 + (lane & 15)) * 256);
  const unsigned rbG = (unsigned)((2*128 + w*16 + (lane & 15)) * 256);
  const unsigned rbO = (unsigned)((3*128 + w*16 + (lane & 15)) * 256);
  const unsigned hwoff = (unsigned)(((w*32 + kg*8) ^ swzB) + b*256);
  const int k0 = w*16 + kg*4;

  // ---- hoist A fragments (W) into registers: ds_read ONCE ----
  // index: A[kslice*4 + gate]
  bf16x8 A[16];
  A[ 0] = *(const bf16x8*)(Wl + rbI + xa0);
  A[ 1] = *(const bf16x8*)(Wl + rbF + xa0);
  A[ 2] = *(const bf16x8*)(Wl + rbG + xa0);
  A[ 3] = *(const bf16x8*)(Wl + rbO + xa0);
  A[ 4] = *(const bf16x8*)(Wl + rbI + xa1);
  A[ 5] = *(const bf16x8*)(Wl + rbF + xa1);
  A[ 6] = *(const bf16x8*)(Wl + rbG + xa1);
  A[ 7] = *(const bf16x8*)(Wl + rbO + xa1);
  A[ 8] = *(const bf16x8*)(Wl + rbI + xa2);
  A[ 9] = *(const bf16x8*)(Wl + rbF + xa2);
  A[10] = *(const bf16x8*)(Wl + rbG + xa2);
  A[11] = *(const bf16x8*)(Wl + rbO + xa2);
  A[12] = *(const bf16x8*)(Wl + rbI + xa3);
  A[13] = *(const bf16x8*)(Wl + rbF + xa3);
  A[14] = *(const bf16x8*)(Wl + rbG + xa3);
  A[15] = *(const bf16x8*)(Wl + rbO + xa3);
  #pragma unroll
  for (int i=0;i<16;i++) asm volatile("" : "+v"(A[i]));

  float c0=0.f, c1=0.f, c2=0.f, c3=0.f;

  // xg preload for s=0
  const float* xq0 = xg + ((size_t)b*256 + 0)*512 + k0;
  f32x4 xgcI = *(const f32x4*)(xq0);
  f32x4 xgcF = *(const f32x4*)(xq0 + 128);
  f32x4 xgcG = *(const f32x4*)(xq0 + 256);
  f32x4 xgcO = *(const f32x4*)(xq0 + 384);

  int cur = 0;
  for (int s=0; s<L_; s++){
    // prefetch xg for s+1 (hidden under this step's MFMA/epilogue)
    int s2 = (s < L_-1) ? s+1 : L_-1;
    const float* xq = xg + ((size_t)b*256 + s2)*512 + k0;
    f32x4 xgnI = *(const f32x4*)(xq);
    f32x4 xgnF = *(const f32x4*)(xq + 128);
    f32x4 xgnG = *(const f32x4*)(xq + 256);
    f32x4 xgnO = *(const f32x4*)(xq + 384);

    // B fragments: h (bf16) from hb[cur]
    const char* hbc = hb + cur*4096 + b*256;
    bf16x8 bf0 = *(const bf16x8*)(hbc + xb0);
    bf16x8 bf1 = *(const bf16x8*)(hbc + xb1);
    bf16x8 bf2 = *(const bf16x8*)(hbc + xb2);
    bf16x8 bf3 = *(const bf16x8*)(hbc + xb3);

    // 16 MFMAs: 4 gate-tiles x 4 k-slices, acc init = xg
    f32x4 aI = xgcI, aF = xgcF, aG = xgcG, aO = xgcO;
    aI = __builtin_amdgcn_mfma_f32_16x16x32_bf16(A[ 0], bf0, aI, 0,0,0);
    aF = __builtin_amdgcn_mfma_f32_16x16x32_bf16(A[ 1], bf0, aF, 0,0,0);
    aG = __builtin_amdgcn_mfma_f32_16x16x32_bf16(A[ 2], bf0, aG, 0,0,0);
    aO = __builtin_amdgcn_mfma_f32_16x16x32_bf16(A[ 3], bf0, aO, 0,0,0);
    aI = __builtin_amdgcn_mfma_f32_16x16x32_bf16(A[ 4], bf1, aI, 0,0,0);
    aF = __builtin_amdgcn_mfma_f32_16x16x32_bf16(A[ 5], bf1, aF, 0,0,0);
    aG = __builtin_amdgcn_mfma_f32_16x16x32_bf16(A[ 6], bf1, aG, 0,0,0);
    aO = __builtin_amdgcn_mfma_f32_16x16x32_bf16(A[ 7], bf1, aO, 0,0,0);
    aI = __builtin_amdgcn_mfma_f32_16x16x32_bf16(A[ 8], bf2, aI, 0,0,0);
    aF = __builtin_amdgcn_mfma_f32_16x16x32_bf16(A[ 9], bf2, aF, 0,0,0);
    aG = __builtin_amdgcn_mfma_f32_16x16x32_bf16(A[10], bf2, aG, 0,0,0);
    aO = __builtin_amdgcn_mfma_f32_16x16x32_bf16(A[11], bf2, aO, 0,0,0);
    aI = __builtin_amdgcn_mfma_f32_16x16x32_bf16(A[12], bf3, aI, 0,0,0);
    aF = __builtin_amdgcn_mfma_f32_16x16x32_bf16(A[13], bf3, aF, 0,0,0);
    aG = __builtin_amdgcn_mfma_f32_16x16x32_bf16(A[14], bf3, aG, 0,0,0);
    aO = __builtin_amdgcn_mfma_f32_16x16x32_bf16(A[15], bf3, aO, 0,0,0);

    // lane-local epilogue: c,h for (k0+reg, b)
    float i0=sigm(aI.x), i1=sigm(aI.y), i2=sigm(aI.z), i3=sigm(aI.w);
    float f0=sigm(aF.x), f1=sigm(aF.y), f2=sigm(aF.z), f3=sigm(aF.w);
    float g0=tanh_fast(aG.x), g1=tanh_fast(aG.y), g2=tanh_fast(aG.z), g3=tanh_fast(aG.w);
    float o0=sigm(aO.x), o1=sigm(aO.y), o2=sigm(aO.z), o3=sigm(aO.w);
    c0 = f0*c0 + i0*g0;  float h0 = o0*tanh_fast(c0);
    c1 = f1*c1 + i1*g1;  float h1 = o1*tanh_fast(c1);
    c2 = f2*c2 + i2*g2;  float h2 = o2*tanh_fast(c2);
    c3 = f3*c3 + i3*g3;  float h3 = o3*tanh_fast(c3);

    // fp32 h -> enc_out
    *(f32x4*)(enc_out + ((size_t)b*256 + s)*128 + k0) = (f32x4){h0,h1,h2,h3};
    // bf16 h -> hb[cur^1]
    u32x2 hp; hp.x = pack_bf2(h0,h1); hp.y = pack_bf2(h2,h3);
    *(u32x2*)(hb + (cur^1)*4096 + hwoff) = hp;

    __syncthreads();
    cur ^= 1;
    xgcI = xgnI; xgcF = xgnF; xgcG = xgnG; xgcO = xgnO;
  }
}

// ---------------- fused: [blocks 0-15] mid chain  /  [blocks 16-31] token agg ----------------
__global__ __launch_bounds__(512) void midagg_kernel(
    const int* __restrict__ src, const int* __restrict__ prev,
    const float* __restrict__ enc_out, const float* __restrict__ cW,
    const float* __restrict__ dstate, const float* __restrict__ emb,
    const float* __restrict__ dWih, const float* __restrict__ db,
    const float* __restrict__ aW, const float* __restrict__ oW,
    const float* __restrict__ ob, float* __restrict__ attn_out,
    const int* __restrict__ stw, float* __restrict__ agg,
    int* __restrict__ replist, int* __restrict__ repcnt)
{
  int t=threadIdx.x;
  if (blockIdx.x >= 16){
    // ======== copy_agg path (first-occurrence aggregation) ========
    int b = blockIdx.x - 16;
    __shared__ int stok[256];
    __shared__ int scnt;
    if (t<256) stok[t] = stw[b*L_+t];
    if (t==0) scnt=0;
    __syncthreads();
    if (t<256){
      int tok = stok[t];
      int first=0;
      while (stok[first]!=tok) first++;
      if (first==t){
        int myidx = atomicAdd(&scnt,1);
        f32x4 acc[32];
        #pragma unroll
        for (int i=0;i<32;i++) acc[i]=(f32x4){0.f,0.f,0.f,0.f};
        for (int l2=t; l2<L_; l2++){
          if (stok[l2]==tok){
            const f32x4* e=(const f32x4*)(enc_out + ((size_t)b*L_+l2)*H_);
            #pragma unroll
            for (int i=0;i<32;i++) acc[i]+=e[i];
          }
        }
        f32x4* dst=(f32x4*)(agg + ((size_t)b*L_+t)*H_);
        #pragma unroll
        for (int i=0;i<32;i++) dst[i]=acc[i];
        replist[b*L_+myidx]=t;
      }
    }
    __syncthreads();
    if (t==0) repcnt[b]=scnt;
    return;
  }

  // ======== mid path: copy scores + copy softmax/state + dec step + attention ========
  int b=blockIdx.x;
  __shared__ float s_scopy[256];
  __shared__ int   mlist[256];
  __shared__ int   mcnt;
  __shared__ __align__(16) float se[128];
  __shared__ float sw[256];
  __shared__ float spart[512];
  __shared__ float sred[4];
  __shared__ __align__(16) float sin_[256];
  __shared__ float sg[512];
  __shared__ __align__(16) float sr[128];
  __shared__ __align__(16) float sq[128];
  __shared__ float sc[256];
  __shared__ __align__(16) float sctx[128];

  if (t==0) mcnt=0;
  __syncthreads();
  if (t<256){
    s_scopy[t]=0.f;
    if (src[b*L_+t]==prev[b]){ int i=atomicAdd(&mcnt,1); mlist[i]=t; }
  }
  __syncthreads();
  for (int mi=0; mi<mcnt; mi++){
    int l = mlist[mi];
    if (t<128) se[t] = enc_out[((size_t)b*L_+l)*H_ + t];
    __syncthreads();
    if (t<128){
      const f32x4* wr = (const f32x4*)(cW + (size_t)t*H_);
      const f32x4* e4 = (const f32x4*)se;
      float acc=0.f;
      #pragma unroll
      for (int i=0;i<32;i++){
        f32x4 wv=wr[i], e=e4[i];
        acc += wv.x*e.x + wv.y*e.y + wv.z*e.z + wv.w*e.w;
      }
      float v = tanhf(acc)*dstate[b*H_+t];
      #pragma unroll
      for (int o=32;o;o>>=1) v += __shfl_down(v,o);
      if ((t&63)==0) sred[t>>6]=v;
    }
    __syncthreads();
    if (t==0) s_scopy[l]=sred[0]+sred[1];
    __syncthreads();
  }

  // softmax over copy scores
  float v = (t<256) ? s_scopy[t] : -INFINITY;
  {
    float m=v;
    #pragma unroll
    for (int o=32;o;o>>=1) m=fmaxf(m,__shfl_down(m,o));
    if (t<256 && (t&63)==0) sred[t>>6]=m;
  }
  __syncthreads();
  float m4 = fmaxf(fmaxf(sred[0],sred[1]),fmaxf(sred[2],sred[3]));
  __syncthreads();
  float e = (t<256) ? __expf(v-m4) : 0.f;
  {
    float z=e;
    #pragma unroll
    for (int o=32;o;o>>=1) z += __shfl_down(z,o);
    if (t<256 && (t&63)==0) sred[t>>6]=z;
  }
  __syncthreads();
  {
    float z4 = sred[0]+sred[1]+sred[2]+sred[3];
    if (t<256) sw[t] = e/z4;
  }
  __syncthreads();

  // copy_state
  {
    int ch=t>>7, h=t&127;
    float acc=0.f;
    const float* eb = enc_out + (size_t)b*L_*H_;
    for (int l=ch*64; l<ch*64+64; l++) acc += sw[l]*eb[(size_t)l*H_+h];
    spart[t]=acc;
  }
  __syncthreads();
  if (t<128){
    float cst = spart[t]+spart[128+t]+spart[256+t]+spart[384+t];
    sin_[128+t]=cst;
    sin_[t]=emb[(size_t)prev[b]*E_+t];
  }
  __syncthreads();

  // decoder single LSTM step (h0=c0=0)
  {
    const f32x4* wr=(const f32x4*)(dWih + (size_t)t*256);
    const f32x4* x4=(const f32x4*)sin_;
    f32x2 d0={db[t],0.f}, d1={0.f,0.f}, d2={0.f,0.f}, d3={0.f,0.f};
    #pragma unroll
    for (int k=0;k<64;k+=4){
      f32x4 xa=x4[k], xb=x4[k+1], xc=x4[k+2], xd=x4[k+3];
      f32x4 wva=wr[k], wvb=wr[k+1], wvc=wr[k+2], wvd=wr[k+3];
      d0 += wva.xy*xa.xy; d1 += wva.zw*xa.zw;
      d2 += wvb.xy*xb.xy; d3 += wvb.zw*xb.zw;
      d0 += wvc.xy*xc.xy; d1 += wvc.zw*xc.zw;
      d2 += wvd.xy*xd.xy; d3 += wvd.zw*xd.zw;
    }
    f32x2 dsm=(d0+d1)+(d2+d3);
    sg[t]=dsm.x+dsm.y;
  }
  __syncthreads();
  if (t<128){
    float iv=sg[t], gv=sg[256+t], ov=sg[384+t];
    float cc = sigm(iv)*tanhf(gv);
    sr[t] = sigm(ov)*tanhf(cc);
  }
  __syncthreads();

  // q = attn_W @ rnn
  if (t<128){
    const f32x4* wr=(const f32x4*)(aW + (size_t)t*H_);
    const f32x4* x4=(const f32x4*)sr;
    float acc=0.f;
    #pragma unroll
    for (int i=0;i<32;i++){
      f32x4 wv=wr[i], x=x4[i];
      acc += wv.x*x.x + wv.y*x.y + wv.z*x.z + wv.w*x.w;
    }
    sq[t]=acc;
  }
  __syncthreads();

  // scores + pad mask
  if (t<256){
    const f32x4* e4=(const f32x4*)(enc_out + ((size_t)b*L_+t)*H_);
    const f32x4* q4=(const f32x4*)sq;
    float acc=0.f;
    #pragma unroll
    for (int i=0;i<32;i++){
      f32x4 ev=e4[i], q=q4[i];
      acc += ev.x*q.x + ev.y*q.y + ev.z*q.z + ev.w*q.w;
    }
    if (src[b*L_+t]==0) acc=-INFINITY;
    sc[t]=acc;
  }
  __syncthreads();

  // attn softmax
  v = (t<256) ? sc[t] : -INFINITY;
  {
    float m=v;
    #pragma unroll
    for (int o=32;o;o>>=1) m=fmaxf(m,__shfl_down(m,o));
    if (t<256 && (t&63)==0) sred[t>>6]=m;
  }
  __syncthreads();
  m4 = fmaxf(fmaxf(sred[0],sred[1]),fmaxf(sred[2],sred[3]));
  __syncthreads();
  e = (t<256) ? __expf(v-m4) : 0.f;
  {
    float z=e;
    #pragma unroll
    for (int o=32;o;o>>=1) z += __shfl_down(z,o);
    if (t<256 && (t&63)==0) sred[t>>6]=z;
  }
  __syncthreads();
  {
    float z4 = sred[0]+sred[1]+sred[2]+sred[3];
    if (t<256) sc[t] = e/z4;
  }
  __syncthreads();

  // ctx
  {
    int ch=t>>7, h=t&127;
    float acc=0.f;
    const float* eb = enc_out + (size_t)b*L_*H_;
    for (int l=ch*64; l<ch*64+64; l++) acc += sc[l]*eb[(size_t)l*H_+h];
    spart[t]=acc;
  }
  __syncthreads();
  if (t<128) sctx[t] = spart[t]+spart[128+t]+spart[256+t]+spart[384+t];
  __syncthreads();

  // attn_out = tanh(out_W @ [rnn,ctx] + out_b)
  if (t<128){
    const f32x4* wr=(const f32x4*)(oW + (size_t)t*256);
    const f32x4* r4=(const f32x4*)sr;
    const f32x4* c4=(const f32x4*)sctx;
    float acc=ob[t];
    #pragma unroll
    for (int i=0;i<32;i++){
      f32x4 wv=wr[i], x=r4[i];
      acc += wv.x*x.x + wv.y*x.y + wv.z*x.z + wv.w*x.w;
    }
    #pragma unroll
    for (int i=0;i<32;i++){
      f32x4 wv=wr[32+i], x=c4[i];
      acc += wv.x*x.x + wv.y*x.y + wv.z*x.z + wv.w*x.w;
    }
    attn_out[b*H_+t]=tanhf(acc);
  }
}

// ---------------- K9: gen logits + masks -> total ----------------
__global__ __launch_bounds__(256) void gen_logits_kernel(
    const float* __restrict__ attn_out, const float* __restrict__ gW,
    const int* __restrict__ oovc, float* __restrict__ total)
{
  __shared__ float sa[B_*H_];
  __shared__ float sw[64*129];
  int t=threadIdx.x;
  int v0=blockIdx.x*64;
  for (int i=t;i<B_*H_;i+=256) sa[i]=attn_out[i];
  for (int i=t;i<64*32;i+=256){
    int r=i>>5, cc=i&31;
    if (v0+r<NV_){
      float4 wv = ((const float4*)(gW + (size_t)(v0+r)*H_))[cc];
      float* dst = sw + r*129 + cc*4;
      dst[0]=wv.x; dst[1]=wv.y; dst[2]=wv.z; dst[3]=wv.w;
    }
  }
  __syncthreads();
  int vl=t&63, bq=t>>6;
  int v=v0+vl;
  if (v>=NV_) return;
  float acc[4]={0.f,0.f,0.f,0.f};
  const float* wrow = sw + vl*129;
  #pragma unroll 8
  for (int h4=0; h4<32; h4++){
    float w0=wrow[h4*4+0], w1=wrow[h4*4+1], w2=wrow[h4*4+2], w3=wrow[h4*4+3];
    #pragma unroll
    for (int k=0;k<4;k++){
      float4 a = ((const float4*)(sa + (bq*4+k)*H_))[h4];
      acc[k] += w0*a.x + w1*a.y + w2*a.z + w3*a.w;
    }
  }
  #pragma unroll
  for (int k=0;k<4;k++){
    int b=bq*4+k;
    float o = (v==1 || v >= V_ + oovc[b]) ? -INFINITY : acc[k];
    total[(size_t)b*NV_ + v] = o;
  }
}

// ---------------- K7b: sparse copy scores added into total ----------------
__global__ __launch_bounds__(128) void copy_score2_kernel(
    const int* __restrict__ stw, const float* __restrict__ agg,
    const float* __restrict__ cW, const float* __restrict__ attn_out,
    const int* __restrict__ replist, const int* __restrict__ repcnt,
    float* __restrict__ total)
{
  int b=blockIdx.x;
  int cnt=repcnt[b];
  int g=threadIdx.x;
  __shared__ __align__(16) float srow[128];
  __shared__ float sred[2];
  float aog = attn_out[b*H_+g];
  f32x4 w[32];
  const f32x4* wrow=(const f32x4*)(cW + (size_t)g*H_);
  #pragma unroll
  for (int i=0;i<32;i++) w[i]=wrow[i];
  for (int ri=blockIdx.y; ri<cnt; ri+=gridDim.y){
    int l = replist[b*L_+ri];
    srow[g] = agg[((size_t)b*L_+l)*H_+g];
    __syncthreads();
    float acc=0.f;
    #pragma unroll
    for (int i=0;i<32;i++){
      f32x4 e=((const f32x4*)srow)[i]; f32x4 wv=w[i];
      acc += wv.x*e.x + wv.y*e.y + wv.z*e.z + wv.w*e.w;
    }
    float v = tanhf(acc)*aog;
    #pragma unroll
    for (int o=32;o;o>>=1) v += __shfl_down(v,o);
    if ((g&63)==0) sred[g>>6]=v;
    __syncthreads();
    if (g==0){
      int vtok = stw[b*L_+l];
      total[(size_t)b*NV_ + vtok] += sred[0]+sred[1];
    }
    __syncthreads();
  }
}

// ---------------- K10: vocab softmax (chunked partials + fused finalize) ----------------
__global__ __launch_bounds__(256) void vocab_pass1_kernel(
    const float* __restrict__ total, float* __restrict__ pmax, float* __restrict__ psum)
{
  int b=blockIdx.x, j=blockIdx.y, t=threadIdx.x;
  int lo=j*CHUNKP_, hi=min(lo+CHUNKP_, NV_);
  const float* row = total + (size_t)b*NV_;
  __shared__ float sred[4];
  float m=-INFINITY;
  for (int i=lo+t;i<hi;i+=256) m=fmaxf(m,row[i]);
  #pragma unroll
  for (int o=32;o;o>>=1) m=fmaxf(m,__shfl_down(m,o));
  if ((t&63)==0) sred[t>>6]=m;
  __syncthreads();
  m = fmaxf(fmaxf(sred[0],sred[1]),fmaxf(sred[2],sred[3]));
  __syncthreads();
  float s=0.f;
  if (m > -INFINITY){
    for (int i=lo+t;i<hi;i+=256) s += __expf(row[i]-m);
  }
  #pragma unroll
  for (int o=32;o;o>>=1) s += __shfl_down(s,o);
  if ((t&63)==0) sred[t>>6]=s;
  __syncthreads();
  if (t==0){ pmax[b*8+j]=m; psum[b*8+j]=sred[0]+sred[1]+sred[2]+sred[3]; }
}

__global__ __launch_bounds__(256) void vocab_norm_kernel(
    float* __restrict__ total, const float* __restrict__ pmax,
    const float* __restrict__ psum)
{
  int b=blockIdx.x, j=blockIdx.y, t=threadIdx.x;
  float M=-INFINITY;
  #pragma unroll
  for (int k=0;k<8;k++) M=fmaxf(M,pmax[b*8+k]);
  float Z=0.f;
  #pragma unroll
  for (int k=0;k<8;k++){
    float pj=pmax[b*8+k];
    Z += (pj > -INFINITY) ? psum[b*8+k]*__expf(pj-M) : 0.f;
  }
  float rz=1.0f/Z;
  int lo=j*CHUNK_, hi=min(lo+CHUNK_, NV_);
  float* row = total + (size_t)b*NV_;
  for (int i=lo+t;i<hi;i+=256) row[i] = __expf(row[i]-M)*rz;
}

// ---------------- launch ----------------
extern "C" void kernel_launch(void* const* d_in, const int* in_sizes, int n_in,
                              void* d_out, int out_size, void* d_ws, size_t ws_size,
                              hipStream_t stream)
{
  const int*   src_tokens = (const int*)d_in[0];
  const int*   prev_tok   = (const int*)d_in[2];
  const int*   stw        = (const int*)d_in[4];
  const int*   oovc       = (const int*)d_in[5];
  const float* dstate     = (const float*)d_in[6];
  const float* emb        = (const float*)d_in[7];
  const float* enc_Wih    = (const float*)d_in[8];
  const float* enc_Whh    = (const float*)d_in[9];
  const float* enc_b      = (const float*)d_in[10];
  const float* dec_Wih    = (const float*)d_in[11];
  const float* dec_b      = (const float*)d_in[13];
  const float* attn_W     = (const float*)d_in[14];
  const float* out_W      = (const float*)d_in[15];
  const float* out_b      = (const float*)d_in[16];
  const float* copy_W     = (const float*)d_in[17];
  const float* gen_W      = (const float*)d_in[18];

  float* out      = (float*)d_out;
  float* total    = out;                                 // B*NV
  float* enc_out  = out + (size_t)B_*NV_;                // B*L*H
  float* attn_out = enc_out + (size_t)B_*L_*H_;          // B*H

  float* ws     = (float*)d_ws;
  float* xg     = ws;                                    // B*L*G4
  float* agg    = xg + (size_t)B_*L_*G4_;                // B*L*H
  float* pmax   = agg + (size_t)B_*L_*H_;                // 128
  float* psum   = pmax + 128;                            // 128
  int*   replist= (int*)(psum + 128);                    // B*L
  int*   repcnt = replist + B_*L_;                       // 16

  enc_xg_kernel<<<B_*L_/16, 512, 0, stream>>>(src_tokens, emb, enc_Wih, enc_b, xg);
  enc_lstm_mfma_kernel<<<1, 512, 0, stream>>>(xg, enc_Whh, enc_out);
  midagg_kernel<<<32, 512, 0, stream>>>(src_tokens, prev_tok, enc_out, copy_W, dstate,
                                        emb, dec_Wih, dec_b, attn_W, out_W, out_b, attn_out,
                                        stw, agg, replist, repcnt);
  gen_logits_kernel<<<(NV_+63)/64, 256, 0, stream>>>(attn_out, gen_W, oovc, total);
  copy_score2_kernel<<<dim3(B_,32), 128, 0, stream>>>(stw, agg, copy_W, attn_out, replist, repcnt, total);
  vocab_pass1_kernel<<<dim3(B_,8), 256, 0, stream>>>(total, pmax, psum);
  vocab_norm_kernel<<<dim3(B_,32), 256, 0, stream>>>(total, pmax, psum);
}